// Round 13
// baseline (145.437 us; speedup 1.0000x reference)
//
#include <hip/hip_runtime.h>
#include <stdint.h>

typedef _Float16 f16;
typedef _Float16 half8 __attribute__((ext_vector_type(8)));
typedef _Float16 half4 __attribute__((ext_vector_type(4)));
typedef _Float16 half2 __attribute__((ext_vector_type(2)));
typedef float floatx4 __attribute__((ext_vector_type(4)));

#define LOG2E 1.44269504088896340736f

// async global->LDS, 16B per lane. LDS dest must be wave-uniform base + lane*16.
__device__ __forceinline__ void async_cp16(const void* g, void* l) {
  __builtin_amdgcn_global_load_lds((const __attribute__((address_space(1))) void*)g,
                                   (__attribute__((address_space(3))) void*)l, 16, 0, 0);
}

// cvt_pkrtz returns __fp16x2; bit-cast to our _Float16-based half2.
__device__ __forceinline__ half2 pkrtz(float a, float b) {
  return __builtin_bit_cast(half2, __builtin_amdgcn_cvt_pkrtz(a, b));
}

// ---------------- fused prep: x transpose->fp16 + weight convert ----------------
__global__ __launch_bounds__(256) void k_prep(const float* __restrict__ x,
                                              f16* __restrict__ XT,
                                              const float* __restrict__ wqkv,
                                              const float* __restrict__ wproj,
                                              f16* __restrict__ WQ, f16* __restrict__ WP) {
  __shared__ f16 sT[64][72];
  const int bid = blockIdx.x;
  const int tid = threadIdx.x;
  if (bid < 576) {
    const int hw0 = (bid % 9) * 64, c0 = ((bid / 9) & 7) * 64, b = bid / 72;
    const int cc = tid >> 6, hwc = tid & 63;
    const float* xb = x + (size_t)b * 294912;
    for (int i = 0; i < 16; ++i) {
      int c = c0 + i * 4 + cc;
      sT[hwc][i * 4 + cc] = (f16)xb[c * 576 + hw0 + hwc];
    }
    __syncthreads();
    const int c_c = tid & 63, rr = tid >> 6;
    f16* xtb = XT + ((size_t)b * 576 + hw0) * 512 + c0;
    for (int j = 0; j < 16; ++j) {
      int r = j * 4 + rr;
      xtb[(size_t)r * 512 + c_c] = sT[r][c_c];
    }
  } else {
    const float SCALE_Q = 0.125f * LOG2E;
    const int total1 = 1536 * 512, total2 = 512 * 512;
    for (int idx = (bid - 576) * 256 + tid; idx < total1 + total2; idx += 128 * 256) {
      if (idx < total1) {
        int row = idx >> 9;
        float v = wqkv[idx];
        if ((row % 192) < 64) v *= SCALE_Q;
        WQ[idx] = (f16)v;
      } else {
        WP[idx - total1] = (f16)wproj[idx - total1];
      }
    }
  }
}

// ---------------- QKV GEMM: 128x128 tile, 8 waves (4m x 2n), dbuf k-loop ----------
// R13: 512 threads — waves/CU 6.75 -> 13.5 (the 4-wave version was occupancy-starved;
// same disease attn had pre-R3). Tile/staging/epilogue logic unchanged from R12.
// Vectorized epilogue via sAcc stride-140 (R12-verified); Vh KEY-INTERLEAVED
// p = 2*(k&15) | (k>>4) (consumed by k_attn's PV 16x16x32; verified R6-R12).
__global__ __launch_bounds__(512, 4) void k_qkv_gemm(const f16* __restrict__ XT,
                                                     const f16* __restrict__ WQ,
                                                     f16* __restrict__ Qh,
                                                     f16* __restrict__ Kh,
                                                     f16* __restrict__ Vh) {
  const int t0 = blockIdx.x * 128, n0 = blockIdx.y * 128;
  __shared__ alignas(16) f16 smem[2 * 16384];  // 64 KB: [buf][A 8192 | B 8192]
  const int tid = threadIdx.x;
  const int wave = tid >> 6, lane = tid & 63, quad = lane >> 4, l16 = lane & 15;
  const int msub = (wave & 3) * 32, nsub = (wave >> 2) * 64;
  const floatx4 fzero = {0.f, 0.f, 0.f, 0.f};
  floatx4 acc[2][4];
  for (int i = 0; i < 2; ++i)
    for (int j = 0; j < 4; ++j) acc[i][j] = fzero;

  auto stage = [&](int buf, int k0) {
    f16* dA = smem + buf * 16384;
    f16* dB = dA + 8192;
#pragma unroll
    for (int p = 0; p < 2; ++p) {
      int e = p * 512 + tid;
      int row = e >> 3, colb = e & 7;
      async_cp16((const char*)XT + ((size_t)(t0 + row) * 512 + k0 + colb * 8) * 2,
                 (char*)dA + e * 16);
      async_cp16((const char*)WQ + ((size_t)(n0 + row) * 512 + k0 + colb * 8) * 2,
                 (char*)dB + e * 16);
    }
  };

  stage(0, 0);
  __syncthreads();
  for (int it = 0; it < 8; ++it) {
    int cur = it & 1;
    if (it < 7) stage(cur ^ 1, (it + 1) * 64);
    const f16* sA = smem + cur * 16384;
    const f16* sB = sA + 8192;
    for (int f = 0; f < 2; ++f) {
      half8 a[2], bfr[4];
      for (int ms = 0; ms < 2; ++ms)
        a[ms] = *(const half8*)&sA[(msub + ms * 16 + l16) * 64 + f * 32 + quad * 8];
      for (int ns = 0; ns < 4; ++ns)
        bfr[ns] = *(const half8*)&sB[(nsub + ns * 16 + l16) * 64 + f * 32 + quad * 8];
      for (int ms = 0; ms < 2; ++ms)
        for (int ns = 0; ns < 4; ++ns)
          acc[ms][ns] =
              __builtin_amdgcn_mfma_f32_16x16x32_f16(a[ms], bfr[ns], acc[ms][ns], 0, 0, 0);
    }
    __syncthreads();
  }

  // ---- phase 1: all acc -> sAcc[row][t], stride 140 f16 (35840 B of 64 KB) ----
  f16* sAcc = smem;
  for (int ms = 0; ms < 2; ++ms) {
    int tl = msub + ms * 16 + quad * 4;
    for (int ns = 0; ns < 4; ++ns) {
      int row = nsub + ns * 16 + l16;
      half4 hv;
      for (int r = 0; r < 4; ++r) hv[r] = (f16)acc[ms][ns][r];
      *(half4*)&sAcc[row * 140 + tl] = hv;
    }
  }
  __syncthreads();

  // ---- phase 2: per 64-row half, coalesced global stores ----
  for (int hsel = 0; hsel < 2; ++hsel) {
    int nrow = n0 + hsel * 64;
    int h = nrow / 192, sel = (nrow % 192) >> 6;  // 0=Q 1=K 2=V
    const f16* sH = sAcc + hsel * 64 * 140;
    if (sel < 2) {
      f16* dst = sel ? Kh : Qh;
      // 1024 units = 128 t x 8 dchunk; lanes cover dchunk fastest (one 128B row / 8 lanes)
#pragma unroll
      for (int p = 0; p < 2; ++p) {
        int unit = p * 512 + tid;
        int t_l = unit >> 3, dc = unit & 7;
        int t = t0 + t_l;
        int b = t / 576, hw = t - b * 576;
        int gh = (b >> 2) * 8 + h, n = (b & 3) * 576 + hw;
        half8 w;
#pragma unroll
        for (int i = 0; i < 8; ++i) w[i] = sH[(dc * 8 + i) * 140 + t_l];
        *(half8*)(dst + ((size_t)gh * 2304 + n) * 64 + dc * 8) = w;
      }
    } else {
      // V: key-interleaved write (32-token groups; 576%32==0 -> no b-straddle)
#pragma unroll
      for (int p = 0; p < 2; ++p) {
        int unit = p * 512 + tid;  // d*16 + gq*4 + u
        int d = unit >> 4, gq = (unit >> 2) & 3, u = unit & 3;
        int t = t0 + gq * 32;
        int b = t / 576, hw = t - b * 576;
        int gh = (b >> 2) * 8 + h, nb = (b & 3) * 576 + hw;
        half4 va = *(const half4*)&sH[d * 140 + gq * 32 + u * 4];
        half4 vb2 = *(const half4*)&sH[d * 140 + gq * 32 + 16 + u * 4];
        half8 w = __builtin_shufflevector(va, vb2, 0, 4, 1, 5, 2, 6, 3, 7);
        *(half8*)(Vh + (size_t)gh * 147456 + (size_t)d * 2304 + nb + u * 8) = w;
      }
    }
  }
}

// ---------------- flash attention: R9-verified design, unchanged ----------------
// 48 queries/block, 6 waves, key-split 2-way; grid 768 = exactly 3/CU.
// K LDS-staged swizzled; V LDS-staged interleaved; PV one mfma 16x16x32 per dt.
// (R6/R7/R10 established: vector global loads in this loop => ~91 us. Staged only.)
__global__ __launch_bounds__(384, 4) void k_attn(const f16* __restrict__ Qh,
                                                 const f16* __restrict__ Kh,
                                                 const f16* __restrict__ Vh,
                                                 f16* __restrict__ AOT) {
  const int mt = blockIdx.x, gh = blockIdx.y;
  const int m0 = mt * 48;
  const int g = gh >> 3, h = gh & 7;
  const f16* Qg = Qh + (size_t)gh * 147456;  // [n][d]
  const f16* Kg = Kh + (size_t)gh * 147456;  // [n][d]
  const f16* Vg = Vh + (size_t)gh * 147456;  // [d][n'] key-interleaved
  __shared__ alignas(16) f16 smem[16384];    // 32 KB
  f16* sK = smem;                            // [str 2][buf 2][32*64]
  f16* sV = smem + 8192;                     // [str 2][buf 2][64*32]
  const int tid = threadIdx.x;
  const int wave = tid >> 6, lane = tid & 63, quad = lane >> 4, l16 = lane & 15;
  const int str = wave & 1, qgrp = wave >> 1;
  const floatx4 fzero = {0.f, 0.f, 0.f, 0.f};
  const int sw = l16 & 7;
  const int vsw = (l16 >> 1) & 3;
  const half2 one2 = {(f16)1.f, (f16)1.f};

  auto stage_kv = [&](int ktile, int buf) {
#pragma unroll
    for (int p = 0; p < 3; ++p) {
      int idx = p * 384 + tid;
      if (idx < 1024) {
        int isV = idx >= 512;
        int rem = idx & 511;
        int st = rem >> 8, unit = rem & 255;
        if (!isV) {
          int row = unit >> 3, cb = unit & 7;
          async_cp16(
              Kg + (size_t)(st * 1152 + ktile * 32 + row) * 64 + ((cb ^ (row & 7)) << 3),
              (char*)(sK + (st * 2 + buf) * 2048) + unit * 16);
        } else {
          int row = unit >> 2, pc = unit & 3;
          async_cp16(Vg + (size_t)row * 2304 + st * 1152 + ktile * 32 +
                         ((pc ^ ((row >> 1) & 3)) << 3),
                     (char*)(sV + (st * 2 + buf) * 2048) + unit * 16);
        }
      }
    }
  };

  half8 qa[2];
  {
    int qrow = m0 + qgrp * 16 + l16;
    qa[0] = *(const half8*)(Qg + (size_t)qrow * 64 + quad * 8);
    qa[1] = *(const half8*)(Qg + (size_t)qrow * 64 + 32 + quad * 8);
  }

  stage_kv(0, 0);
  __syncthreads();
  stage_kv(1, 1);

  float l_lane = 0.f;
  floatx4 o[4];
  for (int dt = 0; dt < 4; ++dt) o[dt] = fzero;

  for (int kt = 0; kt < 36; ++kt) {
    const f16* bK = sK + (str * 2 + (kt & 1)) * 2048;
    const f16* bV = sV + (str * 2 + (kt & 1)) * 2048;

    half8 vb[4];
#pragma unroll
    for (int dt = 0; dt < 4; ++dt)
      vb[dt] = *(const half8*)&bV[(dt * 16 + l16) * 32 + ((quad ^ vsw) << 3)];

    floatx4 ta, tb;
    {
      half8 k0 = *(const half8*)&bK[l16 * 64 + ((quad ^ sw) << 3)];
      half8 k1 = *(const half8*)&bK[l16 * 64 + (((4 + quad) ^ sw) << 3)];
      ta = __builtin_amdgcn_mfma_f32_16x16x32_f16(k0, qa[0], fzero, 0, 0, 0);
      ta = __builtin_amdgcn_mfma_f32_16x16x32_f16(k1, qa[1], ta, 0, 0, 0);
    }
    {
      half8 k0 = *(const half8*)&bK[(16 + l16) * 64 + ((quad ^ sw) << 3)];
      half8 k1 = *(const half8*)&bK[(16 + l16) * 64 + (((4 + quad) ^ sw) << 3)];
      tb = __builtin_amdgcn_mfma_f32_16x16x32_f16(k0, qa[0], fzero, 0, 0, 0);
      tb = __builtin_amdgcn_mfma_f32_16x16x32_f16(k1, qa[1], tb, 0, 0, 0);
    }
    half2 a0 = pkrtz(__builtin_amdgcn_exp2f(ta[0]), __builtin_amdgcn_exp2f(ta[1]));
    half2 a1 = pkrtz(__builtin_amdgcn_exp2f(ta[2]), __builtin_amdgcn_exp2f(ta[3]));
    half2 b0 = pkrtz(__builtin_amdgcn_exp2f(tb[0]), __builtin_amdgcn_exp2f(tb[1]));
    half2 b1 = pkrtz(__builtin_amdgcn_exp2f(tb[2]), __builtin_amdgcn_exp2f(tb[3]));
    l_lane = __builtin_amdgcn_fdot2(a0, one2, l_lane, false);
    l_lane = __builtin_amdgcn_fdot2(a1, one2, l_lane, false);
    l_lane = __builtin_amdgcn_fdot2(b0, one2, l_lane, false);
    l_lane = __builtin_amdgcn_fdot2(b1, one2, l_lane, false);
    half4 pa = __builtin_shufflevector(a0, a1, 0, 1, 2, 3);
    half4 pb = __builtin_shufflevector(b0, b1, 0, 1, 2, 3);
    half8 pf = __builtin_shufflevector(pa, pb, 0, 4, 1, 5, 2, 6, 3, 7);

#pragma unroll
    for (int dt = 0; dt < 4; ++dt)
      o[dt] = __builtin_amdgcn_mfma_f32_16x16x32_f16(pf, vb[dt], o[dt], 0, 0, 0);

    if (kt < 35) {
      __syncthreads();
      if (kt + 2 < 36) stage_kv(kt + 2, kt & 1);
    }
  }

  __syncthreads();
  float* cO = (float*)smem;                   // [qgrp][dt][lane][4]
  float* cL = (float*)((char*)smem + 24576);  // [qgrp][lane]
  if (str == 1) {
    cL[qgrp * 64 + lane] = l_lane;
#pragma unroll
    for (int dt = 0; dt < 4; ++dt)
      *(floatx4*)&cO[((qgrp * 4 + dt) * 64 + lane) * 4] = o[dt];
  }
  __syncthreads();
  if (str == 0) {
    l_lane += cL[qgrp * 64 + lane];
#pragma unroll
    for (int dt = 0; dt < 4; ++dt)
      o[dt] += *(const floatx4*)&cO[((qgrp * 4 + dt) * 64 + lane) * 4];

    l_lane += __shfl_xor(l_lane, 16, 64);
    l_lane += __shfl_xor(l_lane, 32, 64);
    float inv[4];
#pragma unroll
    for (int r = 0; r < 4; ++r) {
      float lr = __shfl(l_lane, quad * 4 + r, 64);
      inv[r] = 1.f / lr;
    }
#pragma unroll
    for (int dt = 0; dt < 4; ++dt)
#pragma unroll
      for (int r = 0; r < 4; ++r) {
        int n_tok = m0 + qgrp * 16 + quad * 4 + r;
        int v = n_tok / 576, hw = n_tok % 576;
        int bb = g * 4 + v;
        int c = h * 64 + dt * 16 + l16;
        AOT[((size_t)bb * 576 + hw) * 512 + c] = (f16)(o[dt][r] * inv[r]);
      }
  }
}

// ---------------- proj GEMM: 64x128 tile, 8 waves (2m x 4n), dbuf k-loop ----------
// R13: 512 threads — waves/CU 4.5 -> 9. Tile/staging/epilogue logic unchanged.
__global__ __launch_bounds__(512, 4) void k_proj_gemm(const f16* __restrict__ AOT,
                                                      const f16* __restrict__ WP,
                                                      const float* __restrict__ bias,
                                                      float* __restrict__ out) {
  const int o0 = blockIdx.x * 64, t0 = blockIdx.y * 128;
  __shared__ alignas(16) f16 smem[2 * 12288];  // 48 KB: [buf][A 4096 | B 8192]
  const int tid = threadIdx.x;
  const int wave = tid >> 6, lane = tid & 63, quad = lane >> 4, l16 = lane & 15;
  const int msub = (wave & 1) * 32, nsub = (wave >> 1) * 32;
  const floatx4 fzero = {0.f, 0.f, 0.f, 0.f};
  floatx4 acc[2][2];
  for (int i = 0; i < 2; ++i)
    for (int j = 0; j < 2; ++j) acc[i][j] = fzero;

  auto stage = [&](int buf, int k0) {
    f16* dA = smem + buf * 12288;
    f16* dB = dA + 4096;
    {
      int e = tid;  // 512 units = 64x64 A tile
      int row = e >> 3, colb = e & 7;
      async_cp16((const char*)WP + ((size_t)(o0 + row) * 512 + k0 + colb * 8) * 2,
                 (char*)dA + e * 16);
    }
#pragma unroll
    for (int p = 0; p < 2; ++p) {
      int e = p * 512 + tid;
      int row = e >> 3, colb = e & 7;
      async_cp16((const char*)AOT + ((size_t)(t0 + row) * 512 + k0 + colb * 8) * 2,
                 (char*)dB + e * 16);
    }
  };

  stage(0, 0);
  __syncthreads();
  for (int it = 0; it < 8; ++it) {
    int cur = it & 1;
    if (it < 7) stage(cur ^ 1, (it + 1) * 64);
    const f16* sA = smem + cur * 12288;
    const f16* sB = sA + 4096;
    for (int f = 0; f < 2; ++f) {
      half8 a[2], bfr[2];
      for (int ms = 0; ms < 2; ++ms)
        a[ms] = *(const half8*)&sA[(msub + ms * 16 + l16) * 64 + f * 32 + quad * 8];
      for (int ns = 0; ns < 2; ++ns)
        bfr[ns] = *(const half8*)&sB[(nsub + ns * 16 + l16) * 64 + f * 32 + quad * 8];
      for (int ms = 0; ms < 2; ++ms)
        for (int ns = 0; ns < 2; ++ns)
          acc[ms][ns] =
              __builtin_amdgcn_mfma_f32_16x16x32_f16(a[ms], bfr[ns], acc[ms][ns], 0, 0, 0);
    }
    __syncthreads();
  }
  for (int ms = 0; ms < 2; ++ms) {
    int o_row = o0 + msub + ms * 16 + quad * 4;
    for (int ns = 0; ns < 2; ++ns) {
      int t = t0 + nsub + ns * 16 + l16;
      int b = t / 576, hw = t % 576;
      for (int r = 0; r < 4; ++r) {
        int orow = o_row + r;
        out[(size_t)b * 294912 + (size_t)orow * 576 + hw] = acc[ms][ns][r] + bias[orow];
      }
    }
  }
}

extern "C" void kernel_launch(void* const* d_in, const int* in_sizes, int n_in,
                              void* d_out, int out_size, void* d_ws, size_t ws_size,
                              hipStream_t stream) {
  const float* x = (const float*)d_in[0];
  const float* wqkv = (const float*)d_in[1];
  const float* wproj = (const float*)d_in[2];
  const float* bias = (const float*)d_in[3];
  float* out = (float*)d_out;
  char* ws = (char*)d_ws;
  f16* XT = (f16*)(ws + 0);          // 4,718,592
  f16* WQ = (f16*)(ws + 4718592);    // 1,572,864
  f16* WP = (f16*)(ws + 6291456);    //   524,288
  f16* Qh = (f16*)(ws + 6815744);    // 4,718,592
  f16* Kh = (f16*)(ws + 11534336);   // 4,718,592
  f16* Vh = (f16*)(ws + 16252928);   // 4,718,592  ([gh][d][n'] key-interleaved)
  f16* AOT = (f16*)(ws + 20971520);  // 4,718,592

  k_prep<<<dim3(704), dim3(256), 0, stream>>>(x, XT, wqkv, wproj, WQ, WP);
  k_qkv_gemm<<<dim3(36, 12), dim3(512), 0, stream>>>(XT, WQ, Qh, Kh, Vh);
  k_attn<<<dim3(48, 16), dim3(384), 0, stream>>>(Qh, Kh, Vh, AOT);
  k_proj_gemm<<<dim3(8, 36), dim3(512), 0, stream>>>(AOT, WP, bias, out);
}

// Round 14
// 137.007 us; speedup vs baseline: 1.0615x; 1.0615x over previous
//
#include <hip/hip_runtime.h>
#include <stdint.h>

typedef _Float16 f16;
typedef _Float16 half8 __attribute__((ext_vector_type(8)));
typedef _Float16 half4 __attribute__((ext_vector_type(4)));
typedef _Float16 half2 __attribute__((ext_vector_type(2)));
typedef float floatx4 __attribute__((ext_vector_type(4)));

#define LOG2E 1.44269504088896340736f

// async global->LDS, 16B per lane. LDS dest must be wave-uniform base + lane*16.
__device__ __forceinline__ void async_cp16(const void* g, void* l) {
  __builtin_amdgcn_global_load_lds((const __attribute__((address_space(1))) void*)g,
                                   (__attribute__((address_space(3))) void*)l, 16, 0, 0);
}

// cvt_pkrtz returns __fp16x2; bit-cast to our _Float16-based half2.
__device__ __forceinline__ half2 pkrtz(float a, float b) {
  return __builtin_bit_cast(half2, __builtin_amdgcn_cvt_pkrtz(a, b));
}

// ---------------- fused prep: x transpose->fp16 + weight convert ----------------
__global__ __launch_bounds__(256) void k_prep(const float* __restrict__ x,
                                              f16* __restrict__ XT,
                                              const float* __restrict__ wqkv,
                                              const float* __restrict__ wproj,
                                              f16* __restrict__ WQ, f16* __restrict__ WP) {
  __shared__ f16 sT[64][72];
  const int bid = blockIdx.x;
  const int tid = threadIdx.x;
  if (bid < 576) {
    const int hw0 = (bid % 9) * 64, c0 = ((bid / 9) & 7) * 64, b = bid / 72;
    const int cc = tid >> 6, hwc = tid & 63;
    const float* xb = x + (size_t)b * 294912;
    for (int i = 0; i < 16; ++i) {
      int c = c0 + i * 4 + cc;
      sT[hwc][i * 4 + cc] = (f16)xb[c * 576 + hw0 + hwc];
    }
    __syncthreads();
    const int c_c = tid & 63, rr = tid >> 6;
    f16* xtb = XT + ((size_t)b * 576 + hw0) * 512 + c0;
    for (int j = 0; j < 16; ++j) {
      int r = j * 4 + rr;
      xtb[(size_t)r * 512 + c_c] = sT[r][c_c];
    }
  } else {
    const float SCALE_Q = 0.125f * LOG2E;
    const int total1 = 1536 * 512, total2 = 512 * 512;
    for (int idx = (bid - 576) * 256 + tid; idx < total1 + total2; idx += 128 * 256) {
      if (idx < total1) {
        int row = idx >> 9;
        float v = wqkv[idx];
        if ((row % 192) < 64) v *= SCALE_Q;
        WQ[idx] = (f16)v;
      } else {
        WP[idx - total1] = (f16)wproj[idx - total1];
      }
    }
  }
}

// ---------------- QKV GEMM: R12-verified (256 thr, dbuf, vectorized epilogue) ------
// (R13's 512-thr variant regressed: LDS reads/MFMA rose 1.5x. Reverted.)
__global__ __launch_bounds__(256) void k_qkv_gemm(const f16* __restrict__ XT,
                                                  const f16* __restrict__ WQ,
                                                  f16* __restrict__ Qh, f16* __restrict__ Kh,
                                                  f16* __restrict__ Vh) {
  const int t0 = blockIdx.x * 128, n0 = blockIdx.y * 128;
  __shared__ alignas(16) f16 smem[2 * 16384];  // 64 KB: [buf][A 8192 | B 8192]
  const int tid = threadIdx.x;
  const int wave = tid >> 6, lane = tid & 63, quad = lane >> 4, l16 = lane & 15;
  const int msub = (wave & 1) * 64, nsub = (wave >> 1) * 64;
  const floatx4 fzero = {0.f, 0.f, 0.f, 0.f};
  floatx4 acc[4][4];
  for (int i = 0; i < 4; ++i)
    for (int j = 0; j < 4; ++j) acc[i][j] = fzero;

  auto stage = [&](int buf, int k0) {
    f16* dA = smem + buf * 16384;
    f16* dB = dA + 8192;
#pragma unroll
    for (int p = 0; p < 4; ++p) {
      int e = p * 256 + tid;
      int row = e >> 3, colb = e & 7;
      async_cp16((const char*)XT + ((size_t)(t0 + row) * 512 + k0 + colb * 8) * 2,
                 (char*)dA + e * 16);
      async_cp16((const char*)WQ + ((size_t)(n0 + row) * 512 + k0 + colb * 8) * 2,
                 (char*)dB + e * 16);
    }
  };

  stage(0, 0);
  __syncthreads();
  for (int it = 0; it < 8; ++it) {
    int cur = it & 1;
    if (it < 7) stage(cur ^ 1, (it + 1) * 64);
    const f16* sA = smem + cur * 16384;
    const f16* sB = sA + 8192;
    for (int f = 0; f < 2; ++f) {
      half8 a[4], bfr[4];
      for (int ms = 0; ms < 4; ++ms)
        a[ms] = *(const half8*)&sA[(msub + ms * 16 + l16) * 64 + f * 32 + quad * 8];
      for (int ns = 0; ns < 4; ++ns)
        bfr[ns] = *(const half8*)&sB[(nsub + ns * 16 + l16) * 64 + f * 32 + quad * 8];
      for (int ms = 0; ms < 4; ++ms)
        for (int ns = 0; ns < 4; ++ns)
          acc[ms][ns] =
              __builtin_amdgcn_mfma_f32_16x16x32_f16(a[ms], bfr[ns], acc[ms][ns], 0, 0, 0);
    }
    __syncthreads();
  }

  // ---- phase 1: all acc -> sAcc[row][t], stride 140 f16 ----
  f16* sAcc = smem;
  for (int ms = 0; ms < 4; ++ms) {
    int tl = msub + ms * 16 + quad * 4;
    for (int ns = 0; ns < 4; ++ns) {
      int row = nsub + ns * 16 + l16;
      half4 hv;
      for (int r = 0; r < 4; ++r) hv[r] = (f16)acc[ms][ns][r];
      *(half4*)&sAcc[row * 140 + tl] = hv;
    }
  }
  __syncthreads();

  // ---- phase 2: per 64-row half, coalesced global stores ----
  for (int hsel = 0; hsel < 2; ++hsel) {
    int nrow = n0 + hsel * 64;
    int h = nrow / 192, sel = (nrow % 192) >> 6;  // 0=Q 1=K 2=V
    const f16* sH = sAcc + hsel * 64 * 140;
    if (sel < 2) {
      f16* dst = sel ? Kh : Qh;
#pragma unroll
      for (int p = 0; p < 4; ++p) {
        int unit = p * 256 + tid;
        int t_l = unit >> 3, dc = unit & 7;
        int t = t0 + t_l;
        int b = t / 576, hw = t - b * 576;
        int gh = (b >> 2) * 8 + h, n = (b & 3) * 576 + hw;
        half8 w;
#pragma unroll
        for (int i = 0; i < 8; ++i) w[i] = sH[(dc * 8 + i) * 140 + t_l];
        *(half8*)(dst + ((size_t)gh * 2304 + n) * 64 + dc * 8) = w;
      }
    } else {
      // V: key-interleaved write (32-token groups; 576%32==0 -> no b-straddle)
#pragma unroll
      for (int p = 0; p < 4; ++p) {
        int unit = p * 256 + tid;  // d*16 + gq*4 + u
        int d = unit >> 4, gq = (unit >> 2) & 3, u = unit & 3;
        int t = t0 + gq * 32;
        int b = t / 576, hw = t - b * 576;
        int gh = (b >> 2) * 8 + h, nb = (b & 3) * 576 + hw;
        half4 va = *(const half4*)&sH[d * 140 + gq * 32 + u * 4];
        half4 vb2 = *(const half4*)&sH[d * 140 + gq * 32 + 16 + u * 4];
        half8 w = __builtin_shufflevector(va, vb2, 0, 4, 1, 5, 2, 6, 3, 7);
        *(half8*)(Vh + (size_t)gh * 147456 + (size_t)d * 2304 + nb + u * 8) = w;
      }
    }
  }
}

// ---------------- flash attention: R9 design + incremental staging pointers -------
// 48 queries/block, 6 waves, key-split 2-way; grid 768 = exactly 3/CU.
// K LDS-staged swizzled; V LDS-staged interleaved; PV one mfma 16x16x32 per dt.
// R14: staging addresses hoisted — ktile sequence is 0..35 in order and each cp16
// unit's global source advances LINEARLY (K +4096 B, V +64 B per tile); LDS dest
// toggles between 2 fixed addresses. Per-kt staging is now 3x{cndmask,cp16,add}.
__global__ __launch_bounds__(384, 4) void k_attn(const f16* __restrict__ Qh,
                                                 const f16* __restrict__ Kh,
                                                 const f16* __restrict__ Vh,
                                                 f16* __restrict__ AOT) {
  const int mt = blockIdx.x, gh = blockIdx.y;
  const int m0 = mt * 48;
  const int g = gh >> 3, h = gh & 7;
  const f16* Qg = Qh + (size_t)gh * 147456;  // [n][d]
  const f16* Kg = Kh + (size_t)gh * 147456;  // [n][d]
  const f16* Vg = Vh + (size_t)gh * 147456;  // [d][n'] key-interleaved
  __shared__ alignas(16) f16 smem[16384];    // 32 KB
  f16* sK = smem;                            // [str 2][buf 2][32*64]
  f16* sV = smem + 8192;                     // [str 2][buf 2][64*32]
  const int tid = threadIdx.x;
  const int wave = tid >> 6, lane = tid & 63, quad = lane >> 4, l16 = lane & 15;
  const int str = wave & 1, qgrp = wave >> 1;
  const floatx4 fzero = {0.f, 0.f, 0.f, 0.f};
  const int sw = l16 & 7;
  const int vsw = (l16 >> 1) & 3;
  const half2 one2 = {(f16)1.f, (f16)1.f};

  // unit descriptors: up to 3 cp16 units/thread (1024 units over 384 threads)
  const char* usrc[3];
  int ustep[3];
  char* ulds0[3];
  char* ulds1[3];
  bool uval[3];
#pragma unroll
  for (int u = 0; u < 3; ++u) {
    int idx = u * 384 + tid;
    uval[u] = idx < 1024;
    usrc[u] = nullptr;
    ustep[u] = 0;
    ulds0[u] = ulds1[u] = nullptr;
    if (uval[u]) {
      int isV = idx >= 512;
      int rem = idx & 511;
      int st = rem >> 8, unit = rem & 255;
      if (!isV) {
        int row = unit >> 3, cb = unit & 7;
        usrc[u] =
            (const char*)(Kg + (size_t)(st * 1152 + row) * 64 + ((cb ^ (row & 7)) << 3));
        ustep[u] = 4096;  // 32 rows x 64 d x 2B per ktile
        ulds0[u] = (char*)(sK + (st * 2 + 0) * 2048) + unit * 16;
        ulds1[u] = (char*)(sK + (st * 2 + 1) * 2048) + unit * 16;
      } else {
        int row = unit >> 2, pc = unit & 3;
        usrc[u] = (const char*)(Vg + (size_t)row * 2304 + st * 1152 +
                                ((pc ^ ((row >> 1) & 3)) << 3));
        ustep[u] = 64;  // 32 keys x 2B per ktile
        ulds0[u] = (char*)(sV + (st * 2 + 0) * 2048) + unit * 16;
        ulds1[u] = (char*)(sV + (st * 2 + 1) * 2048) + unit * 16;
      }
    }
  }
  // stages ktiles strictly in order 0,1,2,...: each call advances sources one step
  auto stage = [&](int buf) {
#pragma unroll
    for (int u = 0; u < 3; ++u)
      if (uval[u]) {
        async_cp16(usrc[u], buf ? ulds1[u] : ulds0[u]);
        usrc[u] += ustep[u];
      }
  };

  half8 qa[2];
  {
    int qrow = m0 + qgrp * 16 + l16;
    qa[0] = *(const half8*)(Qg + (size_t)qrow * 64 + quad * 8);
    qa[1] = *(const half8*)(Qg + (size_t)qrow * 64 + 32 + quad * 8);
  }

  stage(0);  // ktile 0 -> buf 0
  __syncthreads();
  stage(1);  // ktile 1 -> buf 1

  float l_lane = 0.f;
  floatx4 o[4];
  for (int dt = 0; dt < 4; ++dt) o[dt] = fzero;

  for (int kt = 0; kt < 36; ++kt) {
    const f16* bK = sK + (str * 2 + (kt & 1)) * 2048;
    const f16* bV = sV + (str * 2 + (kt & 1)) * 2048;

    half8 vb[4];
#pragma unroll
    for (int dt = 0; dt < 4; ++dt)
      vb[dt] = *(const half8*)&bV[(dt * 16 + l16) * 32 + ((quad ^ vsw) << 3)];

    floatx4 ta, tb;
    {
      half8 k0 = *(const half8*)&bK[l16 * 64 + ((quad ^ sw) << 3)];
      half8 k1 = *(const half8*)&bK[l16 * 64 + (((4 + quad) ^ sw) << 3)];
      ta = __builtin_amdgcn_mfma_f32_16x16x32_f16(k0, qa[0], fzero, 0, 0, 0);
      ta = __builtin_amdgcn_mfma_f32_16x16x32_f16(k1, qa[1], ta, 0, 0, 0);
    }
    {
      half8 k0 = *(const half8*)&bK[(16 + l16) * 64 + ((quad ^ sw) << 3)];
      half8 k1 = *(const half8*)&bK[(16 + l16) * 64 + (((4 + quad) ^ sw) << 3)];
      tb = __builtin_amdgcn_mfma_f32_16x16x32_f16(k0, qa[0], fzero, 0, 0, 0);
      tb = __builtin_amdgcn_mfma_f32_16x16x32_f16(k1, qa[1], tb, 0, 0, 0);
    }
    half2 a0 = pkrtz(__builtin_amdgcn_exp2f(ta[0]), __builtin_amdgcn_exp2f(ta[1]));
    half2 a1 = pkrtz(__builtin_amdgcn_exp2f(ta[2]), __builtin_amdgcn_exp2f(ta[3]));
    half2 b0 = pkrtz(__builtin_amdgcn_exp2f(tb[0]), __builtin_amdgcn_exp2f(tb[1]));
    half2 b1 = pkrtz(__builtin_amdgcn_exp2f(tb[2]), __builtin_amdgcn_exp2f(tb[3]));
    l_lane = __builtin_amdgcn_fdot2(a0, one2, l_lane, false);
    l_lane = __builtin_amdgcn_fdot2(a1, one2, l_lane, false);
    l_lane = __builtin_amdgcn_fdot2(b0, one2, l_lane, false);
    l_lane = __builtin_amdgcn_fdot2(b1, one2, l_lane, false);
    half4 pa = __builtin_shufflevector(a0, a1, 0, 1, 2, 3);
    half4 pb = __builtin_shufflevector(b0, b1, 0, 1, 2, 3);
    half8 pf = __builtin_shufflevector(pa, pb, 0, 4, 1, 5, 2, 6, 3, 7);

#pragma unroll
    for (int dt = 0; dt < 4; ++dt)
      o[dt] = __builtin_amdgcn_mfma_f32_16x16x32_f16(pf, vb[dt], o[dt], 0, 0, 0);

    if (kt < 35) {
      __syncthreads();
      if (kt + 2 < 36) stage(kt & 1);  // ktile kt+2 -> buf (kt&1)
    }
  }

  __syncthreads();
  float* cO = (float*)smem;                   // [qgrp][dt][lane][4]
  float* cL = (float*)((char*)smem + 24576);  // [qgrp][lane]
  if (str == 1) {
    cL[qgrp * 64 + lane] = l_lane;
#pragma unroll
    for (int dt = 0; dt < 4; ++dt)
      *(floatx4*)&cO[((qgrp * 4 + dt) * 64 + lane) * 4] = o[dt];
  }
  __syncthreads();
  if (str == 0) {
    l_lane += cL[qgrp * 64 + lane];
#pragma unroll
    for (int dt = 0; dt < 4; ++dt)
      o[dt] += *(const floatx4*)&cO[((qgrp * 4 + dt) * 64 + lane) * 4];

    l_lane += __shfl_xor(l_lane, 16, 64);
    l_lane += __shfl_xor(l_lane, 32, 64);
    float inv[4];
#pragma unroll
    for (int r = 0; r < 4; ++r) {
      float lr = __shfl(l_lane, quad * 4 + r, 64);
      inv[r] = 1.f / lr;
    }
#pragma unroll
    for (int dt = 0; dt < 4; ++dt)
#pragma unroll
      for (int r = 0; r < 4; ++r) {
        int n_tok = m0 + qgrp * 16 + quad * 4 + r;
        int v = n_tok / 576, hw = n_tok % 576;
        int bb = g * 4 + v;
        int c = h * 64 + dt * 16 + l16;
        AOT[((size_t)bb * 576 + hw) * 512 + c] = (f16)(o[dt][r] * inv[r]);
      }
  }
}

// ---------------- proj GEMM: R12-verified (256 thr, dbuf) ----------
__global__ __launch_bounds__(256) void k_proj_gemm(const f16* __restrict__ AOT,
                                                   const f16* __restrict__ WP,
                                                   const float* __restrict__ bias,
                                                   float* __restrict__ out) {
  const int o0 = blockIdx.x * 64, t0 = blockIdx.y * 128;
  __shared__ alignas(16) f16 smem[2 * 12288];  // 48 KB: [buf][A 4096 | B 8192]
  const int tid = threadIdx.x;
  const int wave = tid >> 6, lane = tid & 63, quad = lane >> 4, l16 = lane & 15;
  const int msub = (wave & 1) * 32, nsub = (wave >> 1) * 64;
  const floatx4 fzero = {0.f, 0.f, 0.f, 0.f};
  floatx4 acc[2][4];
  for (int i = 0; i < 2; ++i)
    for (int j = 0; j < 4; ++j) acc[i][j] = fzero;

  auto stage = [&](int buf, int k0) {
    f16* dA = smem + buf * 12288;
    f16* dB = dA + 4096;
#pragma unroll
    for (int p = 0; p < 2; ++p) {
      int e = p * 256 + tid;
      int row = e >> 3, colb = e & 7;
      async_cp16((const char*)WP + ((size_t)(o0 + row) * 512 + k0 + colb * 8) * 2,
                 (char*)dA + e * 16);
    }
#pragma unroll
    for (int p = 0; p < 4; ++p) {
      int e = p * 256 + tid;
      int row = e >> 3, colb = e & 7;
      async_cp16((const char*)AOT + ((size_t)(t0 + row) * 512 + k0 + colb * 8) * 2,
                 (char*)dB + e * 16);
    }
  };

  stage(0, 0);
  __syncthreads();
  for (int it = 0; it < 8; ++it) {
    int cur = it & 1;
    if (it < 7) stage(cur ^ 1, (it + 1) * 64);
    const f16* sA = smem + cur * 12288;
    const f16* sB = sA + 4096;
    for (int f = 0; f < 2; ++f) {
      half8 a[2], bfr[4];
      for (int ms = 0; ms < 2; ++ms)
        a[ms] = *(const half8*)&sA[(msub + ms * 16 + l16) * 64 + f * 32 + quad * 8];
      for (int ns = 0; ns < 4; ++ns)
        bfr[ns] = *(const half8*)&sB[(nsub + ns * 16 + l16) * 64 + f * 32 + quad * 8];
      for (int ms = 0; ms < 2; ++ms)
        for (int ns = 0; ns < 4; ++ns)
          acc[ms][ns] =
              __builtin_amdgcn_mfma_f32_16x16x32_f16(a[ms], bfr[ns], acc[ms][ns], 0, 0, 0);
    }
    __syncthreads();
  }
  for (int ms = 0; ms < 2; ++ms) {
    int o_row = o0 + msub + ms * 16 + quad * 4;
    for (int ns = 0; ns < 4; ++ns) {
      int t = t0 + nsub + ns * 16 + l16;
      int b = t / 576, hw = t % 576;
      for (int r = 0; r < 4; ++r) {
        int orow = o_row + r;
        out[(size_t)b * 294912 + (size_t)orow * 576 + hw] = acc[ms][ns][r] + bias[orow];
      }
    }
  }
}

extern "C" void kernel_launch(void* const* d_in, const int* in_sizes, int n_in,
                              void* d_out, int out_size, void* d_ws, size_t ws_size,
                              hipStream_t stream) {
  const float* x = (const float*)d_in[0];
  const float* wqkv = (const float*)d_in[1];
  const float* wproj = (const float*)d_in[2];
  const float* bias = (const float*)d_in[3];
  float* out = (float*)d_out;
  char* ws = (char*)d_ws;
  f16* XT = (f16*)(ws + 0);          // 4,718,592
  f16* WQ = (f16*)(ws + 4718592);    // 1,572,864
  f16* WP = (f16*)(ws + 6291456);    //   524,288
  f16* Qh = (f16*)(ws + 6815744);    // 4,718,592
  f16* Kh = (f16*)(ws + 11534336);   // 4,718,592
  f16* Vh = (f16*)(ws + 16252928);   // 4,718,592  ([gh][d][n'] key-interleaved)
  f16* AOT = (f16*)(ws + 20971520);  // 4,718,592

  k_prep<<<dim3(704), dim3(256), 0, stream>>>(x, XT, wqkv, wproj, WQ, WP);
  k_qkv_gemm<<<dim3(36, 12), dim3(256), 0, stream>>>(XT, WQ, Qh, Kh, Vh);
  k_attn<<<dim3(48, 16), dim3(384), 0, stream>>>(Qh, Kh, Vh, AOT);
  k_proj_gemm<<<dim3(8, 36), dim3(256), 0, stream>>>(AOT, WP, bias, out);
}

// Round 15
// 128.407 us; speedup vs baseline: 1.1326x; 1.0670x over previous
//
#include <hip/hip_runtime.h>
#include <stdint.h>

typedef _Float16 f16;
typedef _Float16 half8 __attribute__((ext_vector_type(8)));
typedef _Float16 half4 __attribute__((ext_vector_type(4)));
typedef _Float16 half2 __attribute__((ext_vector_type(2)));
typedef float floatx4 __attribute__((ext_vector_type(4)));

#define LOG2E 1.44269504088896340736f

// async global->LDS, 16B per lane. LDS dest must be wave-uniform base + lane*16.
__device__ __forceinline__ void async_cp16(const void* g, void* l) {
  __builtin_amdgcn_global_load_lds((const __attribute__((address_space(1))) void*)g,
                                   (__attribute__((address_space(3))) void*)l, 16, 0, 0);
}

// cvt_pkrtz returns __fp16x2; bit-cast to our _Float16-based half2.
__device__ __forceinline__ half2 pkrtz(float a, float b) {
  return __builtin_bit_cast(half2, __builtin_amdgcn_cvt_pkrtz(a, b));
}

// ---------------- fused prep: x transpose->fp16 + weight convert ----------------
// R15: transpose phase-2 vectorized (b128 LDS read + half8 store, 2 iters instead of
// 16 scalar f16 stores); weight conversion float4->half4 (4x fewer instrs).
__global__ __launch_bounds__(256) void k_prep(const float* __restrict__ x,
                                              f16* __restrict__ XT,
                                              const float* __restrict__ wqkv,
                                              const float* __restrict__ wproj,
                                              f16* __restrict__ WQ, f16* __restrict__ WP) {
  __shared__ f16 sT[64][72];
  const int bid = blockIdx.x;
  const int tid = threadIdx.x;
  if (bid < 576) {
    const int hw0 = (bid % 9) * 64, c0 = ((bid / 9) & 7) * 64, b = bid / 72;
    const int cc = tid >> 6, hwc = tid & 63;
    const float* xb = x + (size_t)b * 294912;
    for (int i = 0; i < 16; ++i) {
      int c = c0 + i * 4 + cc;
      sT[hwc][i * 4 + cc] = (f16)xb[c * 576 + hw0 + hwc];
    }
    __syncthreads();
    // phase 2: 512 units = 64 rows x 8 c-chunks; b128 LDS read (conflict-free:
    // row stride 36 words -> each bank serves exactly 8 words) + half8 store.
    f16* xtb = XT + ((size_t)b * 576 + hw0) * 512 + c0;
#pragma unroll
    for (int p = 0; p < 2; ++p) {
      int u = p * 256 + tid;
      int r = u >> 3, cc8 = u & 7;
      half8 w = *(const half8*)&sT[r][cc8 * 8];
      *(half8*)(xtb + (size_t)r * 512 + cc8 * 8) = w;
    }
  } else {
    const float SCALE_Q = 0.125f * LOG2E;
    const int total1_f4 = (1536 * 512) / 4;  // 196608
    const int total_f4 = total1_f4 + (512 * 512) / 4;
    for (int i4 = (bid - 576) * 256 + tid; i4 < total_f4; i4 += 128 * 256) {
      if (i4 < total1_f4) {
        int row = (i4 * 4) >> 9;
        floatx4 v = *(const floatx4*)(wqkv + (size_t)i4 * 4);
        if ((row % 192) < 64) {
          v[0] *= SCALE_Q; v[1] *= SCALE_Q; v[2] *= SCALE_Q; v[3] *= SCALE_Q;
        }
        half4 hv;
        for (int j = 0; j < 4; ++j) hv[j] = (f16)v[j];
        *(half4*)(WQ + (size_t)i4 * 4) = hv;
      } else {
        int j4 = i4 - total1_f4;
        floatx4 v = *(const floatx4*)(wproj + (size_t)j4 * 4);
        half4 hv;
        for (int j = 0; j < 4; ++j) hv[j] = (f16)v[j];
        *(half4*)(WP + (size_t)j4 * 4) = hv;
      }
    }
  }
}

// ---------------- QKV GEMM: R12/R14-verified (256 thr, dbuf, vectorized epilogue) --
__global__ __launch_bounds__(256) void k_qkv_gemm(const f16* __restrict__ XT,
                                                  const f16* __restrict__ WQ,
                                                  f16* __restrict__ Qh, f16* __restrict__ Kh,
                                                  f16* __restrict__ Vh) {
  const int t0 = blockIdx.x * 128, n0 = blockIdx.y * 128;
  __shared__ alignas(16) f16 smem[2 * 16384];  // 64 KB: [buf][A 8192 | B 8192]
  const int tid = threadIdx.x;
  const int wave = tid >> 6, lane = tid & 63, quad = lane >> 4, l16 = lane & 15;
  const int msub = (wave & 1) * 64, nsub = (wave >> 1) * 64;
  const floatx4 fzero = {0.f, 0.f, 0.f, 0.f};
  floatx4 acc[4][4];
  for (int i = 0; i < 4; ++i)
    for (int j = 0; j < 4; ++j) acc[i][j] = fzero;

  auto stage = [&](int buf, int k0) {
    f16* dA = smem + buf * 16384;
    f16* dB = dA + 8192;
#pragma unroll
    for (int p = 0; p < 4; ++p) {
      int e = p * 256 + tid;
      int row = e >> 3, colb = e & 7;
      async_cp16((const char*)XT + ((size_t)(t0 + row) * 512 + k0 + colb * 8) * 2,
                 (char*)dA + e * 16);
      async_cp16((const char*)WQ + ((size_t)(n0 + row) * 512 + k0 + colb * 8) * 2,
                 (char*)dB + e * 16);
    }
  };

  stage(0, 0);
  __syncthreads();
  for (int it = 0; it < 8; ++it) {
    int cur = it & 1;
    if (it < 7) stage(cur ^ 1, (it + 1) * 64);
    const f16* sA = smem + cur * 16384;
    const f16* sB = sA + 8192;
    for (int f = 0; f < 2; ++f) {
      half8 a[4], bfr[4];
      for (int ms = 0; ms < 4; ++ms)
        a[ms] = *(const half8*)&sA[(msub + ms * 16 + l16) * 64 + f * 32 + quad * 8];
      for (int ns = 0; ns < 4; ++ns)
        bfr[ns] = *(const half8*)&sB[(nsub + ns * 16 + l16) * 64 + f * 32 + quad * 8];
      for (int ms = 0; ms < 4; ++ms)
        for (int ns = 0; ns < 4; ++ns)
          acc[ms][ns] =
              __builtin_amdgcn_mfma_f32_16x16x32_f16(a[ms], bfr[ns], acc[ms][ns], 0, 0, 0);
    }
    __syncthreads();
  }

  // ---- phase 1: all acc -> sAcc[row][t], stride 140 f16 ----
  f16* sAcc = smem;
  for (int ms = 0; ms < 4; ++ms) {
    int tl = msub + ms * 16 + quad * 4;
    for (int ns = 0; ns < 4; ++ns) {
      int row = nsub + ns * 16 + l16;
      half4 hv;
      for (int r = 0; r < 4; ++r) hv[r] = (f16)acc[ms][ns][r];
      *(half4*)&sAcc[row * 140 + tl] = hv;
    }
  }
  __syncthreads();

  // ---- phase 2: per 64-row half, coalesced global stores ----
  for (int hsel = 0; hsel < 2; ++hsel) {
    int nrow = n0 + hsel * 64;
    int h = nrow / 192, sel = (nrow % 192) >> 6;  // 0=Q 1=K 2=V
    const f16* sH = sAcc + hsel * 64 * 140;
    if (sel < 2) {
      f16* dst = sel ? Kh : Qh;
#pragma unroll
      for (int p = 0; p < 4; ++p) {
        int unit = p * 256 + tid;
        int t_l = unit >> 3, dc = unit & 7;
        int t = t0 + t_l;
        int b = t / 576, hw = t - b * 576;
        int gh = (b >> 2) * 8 + h, n = (b & 3) * 576 + hw;
        half8 w;
#pragma unroll
        for (int i = 0; i < 8; ++i) w[i] = sH[(dc * 8 + i) * 140 + t_l];
        *(half8*)(dst + ((size_t)gh * 2304 + n) * 64 + dc * 8) = w;
      }
    } else {
      // V: key-interleaved write (32-token groups; 576%32==0 -> no b-straddle)
#pragma unroll
      for (int p = 0; p < 4; ++p) {
        int unit = p * 256 + tid;  // d*16 + gq*4 + u
        int d = unit >> 4, gq = (unit >> 2) & 3, u = unit & 3;
        int t = t0 + gq * 32;
        int b = t / 576, hw = t - b * 576;
        int gh = (b >> 2) * 8 + h, nb = (b & 3) * 576 + hw;
        half4 va = *(const half4*)&sH[d * 140 + gq * 32 + u * 4];
        half4 vb2 = *(const half4*)&sH[d * 140 + gq * 32 + 16 + u * 4];
        half8 w = __builtin_shufflevector(va, vb2, 0, 4, 1, 5, 2, 6, 3, 7);
        *(half8*)(Vh + (size_t)gh * 147456 + (size_t)d * 2304 + nb + u * 8) = w;
      }
    }
  }
}

// ---------------- flash attention: R14-verified design, unchanged ----------------
__global__ __launch_bounds__(384, 4) void k_attn(const f16* __restrict__ Qh,
                                                 const f16* __restrict__ Kh,
                                                 const f16* __restrict__ Vh,
                                                 f16* __restrict__ AOT) {
  const int mt = blockIdx.x, gh = blockIdx.y;
  const int m0 = mt * 48;
  const int g = gh >> 3, h = gh & 7;
  const f16* Qg = Qh + (size_t)gh * 147456;  // [n][d]
  const f16* Kg = Kh + (size_t)gh * 147456;  // [n][d]
  const f16* Vg = Vh + (size_t)gh * 147456;  // [d][n'] key-interleaved
  __shared__ alignas(16) f16 smem[16384];    // 32 KB
  f16* sK = smem;                            // [str 2][buf 2][32*64]
  f16* sV = smem + 8192;                     // [str 2][buf 2][64*32]
  const int tid = threadIdx.x;
  const int wave = tid >> 6, lane = tid & 63, quad = lane >> 4, l16 = lane & 15;
  const int str = wave & 1, qgrp = wave >> 1;
  const floatx4 fzero = {0.f, 0.f, 0.f, 0.f};
  const int sw = l16 & 7;
  const int vsw = (l16 >> 1) & 3;
  const half2 one2 = {(f16)1.f, (f16)1.f};

  const char* usrc[3];
  int ustep[3];
  char* ulds0[3];
  char* ulds1[3];
  bool uval[3];
#pragma unroll
  for (int u = 0; u < 3; ++u) {
    int idx = u * 384 + tid;
    uval[u] = idx < 1024;
    usrc[u] = nullptr;
    ustep[u] = 0;
    ulds0[u] = ulds1[u] = nullptr;
    if (uval[u]) {
      int isV = idx >= 512;
      int rem = idx & 511;
      int st = rem >> 8, unit = rem & 255;
      if (!isV) {
        int row = unit >> 3, cb = unit & 7;
        usrc[u] =
            (const char*)(Kg + (size_t)(st * 1152 + row) * 64 + ((cb ^ (row & 7)) << 3));
        ustep[u] = 4096;
        ulds0[u] = (char*)(sK + (st * 2 + 0) * 2048) + unit * 16;
        ulds1[u] = (char*)(sK + (st * 2 + 1) * 2048) + unit * 16;
      } else {
        int row = unit >> 2, pc = unit & 3;
        usrc[u] = (const char*)(Vg + (size_t)row * 2304 + st * 1152 +
                                ((pc ^ ((row >> 1) & 3)) << 3));
        ustep[u] = 64;
        ulds0[u] = (char*)(sV + (st * 2 + 0) * 2048) + unit * 16;
        ulds1[u] = (char*)(sV + (st * 2 + 1) * 2048) + unit * 16;
      }
    }
  }
  auto stage = [&](int buf) {
#pragma unroll
    for (int u = 0; u < 3; ++u)
      if (uval[u]) {
        async_cp16(usrc[u], buf ? ulds1[u] : ulds0[u]);
        usrc[u] += ustep[u];
      }
  };

  half8 qa[2];
  {
    int qrow = m0 + qgrp * 16 + l16;
    qa[0] = *(const half8*)(Qg + (size_t)qrow * 64 + quad * 8);
    qa[1] = *(const half8*)(Qg + (size_t)qrow * 64 + 32 + quad * 8);
  }

  stage(0);
  __syncthreads();
  stage(1);

  float l_lane = 0.f;
  floatx4 o[4];
  for (int dt = 0; dt < 4; ++dt) o[dt] = fzero;

  for (int kt = 0; kt < 36; ++kt) {
    const f16* bK = sK + (str * 2 + (kt & 1)) * 2048;
    const f16* bV = sV + (str * 2 + (kt & 1)) * 2048;

    half8 vb[4];
#pragma unroll
    for (int dt = 0; dt < 4; ++dt)
      vb[dt] = *(const half8*)&bV[(dt * 16 + l16) * 32 + ((quad ^ vsw) << 3)];

    floatx4 ta, tb;
    {
      half8 k0 = *(const half8*)&bK[l16 * 64 + ((quad ^ sw) << 3)];
      half8 k1 = *(const half8*)&bK[l16 * 64 + (((4 + quad) ^ sw) << 3)];
      ta = __builtin_amdgcn_mfma_f32_16x16x32_f16(k0, qa[0], fzero, 0, 0, 0);
      ta = __builtin_amdgcn_mfma_f32_16x16x32_f16(k1, qa[1], ta, 0, 0, 0);
    }
    {
      half8 k0 = *(const half8*)&bK[(16 + l16) * 64 + ((quad ^ sw) << 3)];
      half8 k1 = *(const half8*)&bK[(16 + l16) * 64 + (((4 + quad) ^ sw) << 3)];
      tb = __builtin_amdgcn_mfma_f32_16x16x32_f16(k0, qa[0], fzero, 0, 0, 0);
      tb = __builtin_amdgcn_mfma_f32_16x16x32_f16(k1, qa[1], tb, 0, 0, 0);
    }
    half2 a0 = pkrtz(__builtin_amdgcn_exp2f(ta[0]), __builtin_amdgcn_exp2f(ta[1]));
    half2 a1 = pkrtz(__builtin_amdgcn_exp2f(ta[2]), __builtin_amdgcn_exp2f(ta[3]));
    half2 b0 = pkrtz(__builtin_amdgcn_exp2f(tb[0]), __builtin_amdgcn_exp2f(tb[1]));
    half2 b1 = pkrtz(__builtin_amdgcn_exp2f(tb[2]), __builtin_amdgcn_exp2f(tb[3]));
    l_lane = __builtin_amdgcn_fdot2(a0, one2, l_lane, false);
    l_lane = __builtin_amdgcn_fdot2(a1, one2, l_lane, false);
    l_lane = __builtin_amdgcn_fdot2(b0, one2, l_lane, false);
    l_lane = __builtin_amdgcn_fdot2(b1, one2, l_lane, false);
    half4 pa = __builtin_shufflevector(a0, a1, 0, 1, 2, 3);
    half4 pb = __builtin_shufflevector(b0, b1, 0, 1, 2, 3);
    half8 pf = __builtin_shufflevector(pa, pb, 0, 4, 1, 5, 2, 6, 3, 7);

#pragma unroll
    for (int dt = 0; dt < 4; ++dt)
      o[dt] = __builtin_amdgcn_mfma_f32_16x16x32_f16(pf, vb[dt], o[dt], 0, 0, 0);

    if (kt < 35) {
      __syncthreads();
      if (kt + 2 < 36) stage(kt & 1);
    }
  }

  __syncthreads();
  float* cO = (float*)smem;                   // [qgrp][dt][lane][4]
  float* cL = (float*)((char*)smem + 24576);  // [qgrp][lane]
  if (str == 1) {
    cL[qgrp * 64 + lane] = l_lane;
#pragma unroll
    for (int dt = 0; dt < 4; ++dt)
      *(floatx4*)&cO[((qgrp * 4 + dt) * 64 + lane) * 4] = o[dt];
  }
  __syncthreads();
  if (str == 0) {
    l_lane += cL[qgrp * 64 + lane];
#pragma unroll
    for (int dt = 0; dt < 4; ++dt)
      o[dt] += *(const floatx4*)&cO[((qgrp * 4 + dt) * 64 + lane) * 4];

    l_lane += __shfl_xor(l_lane, 16, 64);
    l_lane += __shfl_xor(l_lane, 32, 64);
    float inv[4];
#pragma unroll
    for (int r = 0; r < 4; ++r) {
      float lr = __shfl(l_lane, quad * 4 + r, 64);
      inv[r] = 1.f / lr;
    }
#pragma unroll
    for (int dt = 0; dt < 4; ++dt)
#pragma unroll
      for (int r = 0; r < 4; ++r) {
        int n_tok = m0 + qgrp * 16 + quad * 4 + r;
        int v = n_tok / 576, hw = n_tok % 576;
        int bb = g * 4 + v;
        int c = h * 64 + dt * 16 + l16;
        AOT[((size_t)bb * 576 + hw) * 512 + c] = (f16)(o[dt][r] * inv[r]);
      }
  }
}

// ---------------- proj GEMM: 64(o) x 96(t) tiles, dbuf — grid 384 = 1.5/CU -------
// R15: t-tile 128->96 (96 | 576, no b-straddle). Balance 56% -> 75%
// (288 blocks left 224 CUs idle half the kernel). 4 waves: 2o x 3t frags.
__global__ __launch_bounds__(256) void k_proj_gemm(const f16* __restrict__ AOT,
                                                   const f16* __restrict__ WP,
                                                   const float* __restrict__ bias,
                                                   float* __restrict__ out) {
  const int o0 = blockIdx.x * 64, t0 = blockIdx.y * 96;
  __shared__ alignas(16) f16 smem[2 * 10240];  // 40 KB: [buf][A 4096 | B 6144]
  const int tid = threadIdx.x;
  const int wave = tid >> 6, lane = tid & 63, quad = lane >> 4, l16 = lane & 15;
  const int msub = (wave & 1) * 32, nsub = (wave >> 1) * 48;
  const floatx4 fzero = {0.f, 0.f, 0.f, 0.f};
  floatx4 acc[2][3];
  for (int i = 0; i < 2; ++i)
    for (int j = 0; j < 3; ++j) acc[i][j] = fzero;

  auto stage = [&](int buf, int k0) {
    f16* dA = smem + buf * 10240;
    f16* dB = dA + 4096;
#pragma unroll
    for (int p = 0; p < 2; ++p) {
      int e = p * 256 + tid;
      int row = e >> 3, colb = e & 7;
      async_cp16((const char*)WP + ((size_t)(o0 + row) * 512 + k0 + colb * 8) * 2,
                 (char*)dA + e * 16);
    }
#pragma unroll
    for (int p = 0; p < 3; ++p) {
      int e = p * 256 + tid;
      int row = e >> 3, colb = e & 7;
      async_cp16((const char*)AOT + ((size_t)(t0 + row) * 512 + k0 + colb * 8) * 2,
                 (char*)dB + e * 16);
    }
  };

  stage(0, 0);
  __syncthreads();
  for (int it = 0; it < 8; ++it) {
    int cur = it & 1;
    if (it < 7) stage(cur ^ 1, (it + 1) * 64);
    const f16* sA = smem + cur * 10240;
    const f16* sB = sA + 4096;
    for (int f = 0; f < 2; ++f) {
      half8 a[2], bfr[3];
      for (int ms = 0; ms < 2; ++ms)
        a[ms] = *(const half8*)&sA[(msub + ms * 16 + l16) * 64 + f * 32 + quad * 8];
      for (int ns = 0; ns < 3; ++ns)
        bfr[ns] = *(const half8*)&sB[(nsub + ns * 16 + l16) * 64 + f * 32 + quad * 8];
      for (int ms = 0; ms < 2; ++ms)
        for (int ns = 0; ns < 3; ++ns)
          acc[ms][ns] =
              __builtin_amdgcn_mfma_f32_16x16x32_f16(a[ms], bfr[ns], acc[ms][ns], 0, 0, 0);
    }
    __syncthreads();
  }
  for (int ms = 0; ms < 2; ++ms) {
    int o_row = o0 + msub + ms * 16 + quad * 4;
    for (int ns = 0; ns < 3; ++ns) {
      int t = t0 + nsub + ns * 16 + l16;
      int b = t / 576, hw = t % 576;
      for (int r = 0; r < 4; ++r) {
        int orow = o_row + r;
        out[(size_t)b * 294912 + (size_t)orow * 576 + hw] = acc[ms][ns][r] + bias[orow];
      }
    }
  }
}

extern "C" void kernel_launch(void* const* d_in, const int* in_sizes, int n_in,
                              void* d_out, int out_size, void* d_ws, size_t ws_size,
                              hipStream_t stream) {
  const float* x = (const float*)d_in[0];
  const float* wqkv = (const float*)d_in[1];
  const float* wproj = (const float*)d_in[2];
  const float* bias = (const float*)d_in[3];
  float* out = (float*)d_out;
  char* ws = (char*)d_ws;
  f16* XT = (f16*)(ws + 0);          // 4,718,592
  f16* WQ = (f16*)(ws + 4718592);    // 1,572,864
  f16* WP = (f16*)(ws + 6291456);    //   524,288
  f16* Qh = (f16*)(ws + 6815744);    // 4,718,592
  f16* Kh = (f16*)(ws + 11534336);   // 4,718,592
  f16* Vh = (f16*)(ws + 16252928);   // 4,718,592  ([gh][d][n'] key-interleaved)
  f16* AOT = (f16*)(ws + 20971520);  // 4,718,592

  k_prep<<<dim3(704), dim3(256), 0, stream>>>(x, XT, wqkv, wproj, WQ, WP);
  k_qkv_gemm<<<dim3(36, 12), dim3(256), 0, stream>>>(XT, WQ, Qh, Kh, Vh);
  k_attn<<<dim3(48, 16), dim3(384), 0, stream>>>(Qh, Kh, Vh, AOT);
  k_proj_gemm<<<dim3(8, 48), dim3(256), 0, stream>>>(AOT, WP, bias, out);
}

// Round 16
// 127.937 us; speedup vs baseline: 1.1368x; 1.0037x over previous
//
#include <hip/hip_runtime.h>
#include <stdint.h>

typedef _Float16 f16;
typedef _Float16 half8 __attribute__((ext_vector_type(8)));
typedef _Float16 half4 __attribute__((ext_vector_type(4)));
typedef _Float16 half2 __attribute__((ext_vector_type(2)));
typedef float floatx4 __attribute__((ext_vector_type(4)));

#define LOG2E 1.44269504088896340736f

// async global->LDS, 16B per lane. LDS dest must be wave-uniform base + lane*16.
__device__ __forceinline__ void async_cp16(const void* g, void* l) {
  __builtin_amdgcn_global_load_lds((const __attribute__((address_space(1))) void*)g,
                                   (__attribute__((address_space(3))) void*)l, 16, 0, 0);
}

// cvt_pkrtz returns __fp16x2; bit-cast to our _Float16-based half2.
__device__ __forceinline__ half2 pkrtz(float a, float b) {
  return __builtin_bit_cast(half2, __builtin_amdgcn_cvt_pkrtz(a, b));
}

// ---------------- fused prep: x transpose->fp16 + weight convert (R15-verified) ----
__global__ __launch_bounds__(256) void k_prep(const float* __restrict__ x,
                                              f16* __restrict__ XT,
                                              const float* __restrict__ wqkv,
                                              const float* __restrict__ wproj,
                                              f16* __restrict__ WQ, f16* __restrict__ WP) {
  __shared__ f16 sT[64][72];
  const int bid = blockIdx.x;
  const int tid = threadIdx.x;
  if (bid < 576) {
    const int hw0 = (bid % 9) * 64, c0 = ((bid / 9) & 7) * 64, b = bid / 72;
    const int cc = tid >> 6, hwc = tid & 63;
    const float* xb = x + (size_t)b * 294912;
    for (int i = 0; i < 16; ++i) {
      int c = c0 + i * 4 + cc;
      sT[hwc][i * 4 + cc] = (f16)xb[c * 576 + hw0 + hwc];
    }
    __syncthreads();
    f16* xtb = XT + ((size_t)b * 576 + hw0) * 512 + c0;
#pragma unroll
    for (int p = 0; p < 2; ++p) {
      int u = p * 256 + tid;
      int r = u >> 3, cc8 = u & 7;
      half8 w = *(const half8*)&sT[r][cc8 * 8];
      *(half8*)(xtb + (size_t)r * 512 + cc8 * 8) = w;
    }
  } else {
    const float SCALE_Q = 0.125f * LOG2E;
    const int total1_f4 = (1536 * 512) / 4;  // 196608
    const int total_f4 = total1_f4 + (512 * 512) / 4;
    for (int i4 = (bid - 576) * 256 + tid; i4 < total_f4; i4 += 128 * 256) {
      if (i4 < total1_f4) {
        int row = (i4 * 4) >> 9;
        floatx4 v = *(const floatx4*)(wqkv + (size_t)i4 * 4);
        if ((row % 192) < 64) {
          v[0] *= SCALE_Q; v[1] *= SCALE_Q; v[2] *= SCALE_Q; v[3] *= SCALE_Q;
        }
        half4 hv;
        for (int j = 0; j < 4; ++j) hv[j] = (f16)v[j];
        *(half4*)(WQ + (size_t)i4 * 4) = hv;
      } else {
        int j4 = i4 - total1_f4;
        floatx4 v = *(const floatx4*)(wproj + (size_t)j4 * 4);
        half4 hv;
        for (int j = 0; j < 4; ++j) hv[j] = (f16)v[j];
        *(half4*)(WP + (size_t)j4 * 4) = hv;
      }
    }
  }
}

// ---------------- QKV GEMM: R12/R14-verified (256 thr, dbuf, vectorized epilogue) --
__global__ __launch_bounds__(256) void k_qkv_gemm(const f16* __restrict__ XT,
                                                  const f16* __restrict__ WQ,
                                                  f16* __restrict__ Qh, f16* __restrict__ Kh,
                                                  f16* __restrict__ Vh) {
  const int t0 = blockIdx.x * 128, n0 = blockIdx.y * 128;
  __shared__ alignas(16) f16 smem[2 * 16384];  // 64 KB: [buf][A 8192 | B 8192]
  const int tid = threadIdx.x;
  const int wave = tid >> 6, lane = tid & 63, quad = lane >> 4, l16 = lane & 15;
  const int msub = (wave & 1) * 64, nsub = (wave >> 1) * 64;
  const floatx4 fzero = {0.f, 0.f, 0.f, 0.f};
  floatx4 acc[4][4];
  for (int i = 0; i < 4; ++i)
    for (int j = 0; j < 4; ++j) acc[i][j] = fzero;

  auto stage = [&](int buf, int k0) {
    f16* dA = smem + buf * 16384;
    f16* dB = dA + 8192;
#pragma unroll
    for (int p = 0; p < 4; ++p) {
      int e = p * 256 + tid;
      int row = e >> 3, colb = e & 7;
      async_cp16((const char*)XT + ((size_t)(t0 + row) * 512 + k0 + colb * 8) * 2,
                 (char*)dA + e * 16);
      async_cp16((const char*)WQ + ((size_t)(n0 + row) * 512 + k0 + colb * 8) * 2,
                 (char*)dB + e * 16);
    }
  };

  stage(0, 0);
  __syncthreads();
  for (int it = 0; it < 8; ++it) {
    int cur = it & 1;
    if (it < 7) stage(cur ^ 1, (it + 1) * 64);
    const f16* sA = smem + cur * 16384;
    const f16* sB = sA + 8192;
    for (int f = 0; f < 2; ++f) {
      half8 a[4], bfr[4];
      for (int ms = 0; ms < 4; ++ms)
        a[ms] = *(const half8*)&sA[(msub + ms * 16 + l16) * 64 + f * 32 + quad * 8];
      for (int ns = 0; ns < 4; ++ns)
        bfr[ns] = *(const half8*)&sB[(nsub + ns * 16 + l16) * 64 + f * 32 + quad * 8];
      for (int ms = 0; ms < 4; ++ms)
        for (int ns = 0; ns < 4; ++ns)
          acc[ms][ns] =
              __builtin_amdgcn_mfma_f32_16x16x32_f16(a[ms], bfr[ns], acc[ms][ns], 0, 0, 0);
    }
    __syncthreads();
  }

  // ---- phase 1: all acc -> sAcc[row][t], stride 140 f16 ----
  f16* sAcc = smem;
  for (int ms = 0; ms < 4; ++ms) {
    int tl = msub + ms * 16 + quad * 4;
    for (int ns = 0; ns < 4; ++ns) {
      int row = nsub + ns * 16 + l16;
      half4 hv;
      for (int r = 0; r < 4; ++r) hv[r] = (f16)acc[ms][ns][r];
      *(half4*)&sAcc[row * 140 + tl] = hv;
    }
  }
  __syncthreads();

  // ---- phase 2: per 64-row half, coalesced global stores ----
  for (int hsel = 0; hsel < 2; ++hsel) {
    int nrow = n0 + hsel * 64;
    int h = nrow / 192, sel = (nrow % 192) >> 6;  // 0=Q 1=K 2=V
    const f16* sH = sAcc + hsel * 64 * 140;
    if (sel < 2) {
      f16* dst = sel ? Kh : Qh;
#pragma unroll
      for (int p = 0; p < 4; ++p) {
        int unit = p * 256 + tid;
        int t_l = unit >> 3, dc = unit & 7;
        int t = t0 + t_l;
        int b = t / 576, hw = t - b * 576;
        int gh = (b >> 2) * 8 + h, n = (b & 3) * 576 + hw;
        half8 w;
#pragma unroll
        for (int i = 0; i < 8; ++i) w[i] = sH[(dc * 8 + i) * 140 + t_l];
        *(half8*)(dst + ((size_t)gh * 2304 + n) * 64 + dc * 8) = w;
      }
    } else {
      // V: key-interleaved write (32-token groups; 576%32==0 -> no b-straddle)
#pragma unroll
      for (int p = 0; p < 4; ++p) {
        int unit = p * 256 + tid;  // d*16 + gq*4 + u
        int d = unit >> 4, gq = (unit >> 2) & 3, u = unit & 3;
        int t = t0 + gq * 32;
        int b = t / 576, hw = t - b * 576;
        int gh = (b >> 2) * 8 + h, nb = (b & 3) * 576 + hw;
        half4 va = *(const half4*)&sH[d * 140 + gq * 32 + u * 4];
        half4 vb2 = *(const half4*)&sH[d * 140 + gq * 32 + 16 + u * 4];
        half8 w = __builtin_shufflevector(va, vb2, 0, 4, 1, 5, 2, 6, 3, 7);
        *(half8*)(Vh + (size_t)gh * 147456 + (size_t)d * 2304 + nb + u * 8) = w;
      }
    }
  }
}

// ---------------- flash attention: R14 design + kt x2 unroll (static buffers) -----
__global__ __launch_bounds__(384, 4) void k_attn(const f16* __restrict__ Qh,
                                                 const f16* __restrict__ Kh,
                                                 const f16* __restrict__ Vh,
                                                 f16* __restrict__ AOT) {
  const int mt = blockIdx.x, gh = blockIdx.y;
  const int m0 = mt * 48;
  const int g = gh >> 3, h = gh & 7;
  const f16* Qg = Qh + (size_t)gh * 147456;  // [n][d]
  const f16* Kg = Kh + (size_t)gh * 147456;  // [n][d]
  const f16* Vg = Vh + (size_t)gh * 147456;  // [d][n'] key-interleaved
  __shared__ alignas(16) f16 smem[16384];    // 32 KB
  f16* sK = smem;                            // [str 2][buf 2][32*64]
  f16* sV = smem + 8192;                     // [str 2][buf 2][64*32]
  const int tid = threadIdx.x;
  const int wave = tid >> 6, lane = tid & 63, quad = lane >> 4, l16 = lane & 15;
  const int str = wave & 1, qgrp = wave >> 1;
  const floatx4 fzero = {0.f, 0.f, 0.f, 0.f};
  const int sw = l16 & 7;
  const int vsw = (l16 >> 1) & 3;
  const half2 one2 = {(f16)1.f, (f16)1.f};

  const char* usrc[3];
  int ustep[3];
  char* ulds0[3];
  char* ulds1[3];
  bool uval[3];
#pragma unroll
  for (int u = 0; u < 3; ++u) {
    int idx = u * 384 + tid;
    uval[u] = idx < 1024;
    usrc[u] = nullptr;
    ustep[u] = 0;
    ulds0[u] = ulds1[u] = nullptr;
    if (uval[u]) {
      int isV = idx >= 512;
      int rem = idx & 511;
      int st = rem >> 8, unit = rem & 255;
      if (!isV) {
        int row = unit >> 3, cb = unit & 7;
        usrc[u] =
            (const char*)(Kg + (size_t)(st * 1152 + row) * 64 + ((cb ^ (row & 7)) << 3));
        ustep[u] = 4096;
        ulds0[u] = (char*)(sK + (st * 2 + 0) * 2048) + unit * 16;
        ulds1[u] = (char*)(sK + (st * 2 + 1) * 2048) + unit * 16;
      } else {
        int row = unit >> 2, pc = unit & 3;
        usrc[u] = (const char*)(Vg + (size_t)row * 2304 + st * 1152 +
                                ((pc ^ ((row >> 1) & 3)) << 3));
        ustep[u] = 64;
        ulds0[u] = (char*)(sV + (st * 2 + 0) * 2048) + unit * 16;
        ulds1[u] = (char*)(sV + (st * 2 + 1) * 2048) + unit * 16;
      }
    }
  }
  auto stage0 = [&]() {
#pragma unroll
    for (int u = 0; u < 3; ++u)
      if (uval[u]) {
        async_cp16(usrc[u], ulds0[u]);
        usrc[u] += ustep[u];
      }
  };
  auto stage1 = [&]() {
#pragma unroll
    for (int u = 0; u < 3; ++u)
      if (uval[u]) {
        async_cp16(usrc[u], ulds1[u]);
        usrc[u] += ustep[u];
      }
  };

  half8 qa[2];
  {
    int qrow = m0 + qgrp * 16 + l16;
    qa[0] = *(const half8*)(Qg + (size_t)qrow * 64 + quad * 8);
    qa[1] = *(const half8*)(Qg + (size_t)qrow * 64 + 32 + quad * 8);
  }

  stage0();
  __syncthreads();
  stage1();

  float l_lane = 0.f;
  floatx4 o[4];
  for (int dt = 0; dt < 4; ++dt) o[dt] = fzero;

  // static per-parity buffer pointers (no per-iteration (kt&1) selects)
  const f16* bK0 = sK + (str * 2 + 0) * 2048;
  const f16* bK1 = sK + (str * 2 + 1) * 2048;
  const f16* bV0 = sV + (str * 2 + 0) * 2048;
  const f16* bV1 = sV + (str * 2 + 1) * 2048;

  auto body = [&](const f16* bK, const f16* bV) {
    half8 vb[4];
#pragma unroll
    for (int dt = 0; dt < 4; ++dt)
      vb[dt] = *(const half8*)&bV[(dt * 16 + l16) * 32 + ((quad ^ vsw) << 3)];

    floatx4 ta, tb;
    {
      half8 k0 = *(const half8*)&bK[l16 * 64 + ((quad ^ sw) << 3)];
      half8 k1 = *(const half8*)&bK[l16 * 64 + (((4 + quad) ^ sw) << 3)];
      ta = __builtin_amdgcn_mfma_f32_16x16x32_f16(k0, qa[0], fzero, 0, 0, 0);
      ta = __builtin_amdgcn_mfma_f32_16x16x32_f16(k1, qa[1], ta, 0, 0, 0);
    }
    {
      half8 k0 = *(const half8*)&bK[(16 + l16) * 64 + ((quad ^ sw) << 3)];
      half8 k1 = *(const half8*)&bK[(16 + l16) * 64 + (((4 + quad) ^ sw) << 3)];
      tb = __builtin_amdgcn_mfma_f32_16x16x32_f16(k0, qa[0], fzero, 0, 0, 0);
      tb = __builtin_amdgcn_mfma_f32_16x16x32_f16(k1, qa[1], tb, 0, 0, 0);
    }
    half2 a0 = pkrtz(__builtin_amdgcn_exp2f(ta[0]), __builtin_amdgcn_exp2f(ta[1]));
    half2 a1 = pkrtz(__builtin_amdgcn_exp2f(ta[2]), __builtin_amdgcn_exp2f(ta[3]));
    half2 b0 = pkrtz(__builtin_amdgcn_exp2f(tb[0]), __builtin_amdgcn_exp2f(tb[1]));
    half2 b1 = pkrtz(__builtin_amdgcn_exp2f(tb[2]), __builtin_amdgcn_exp2f(tb[3]));
    l_lane = __builtin_amdgcn_fdot2(a0, one2, l_lane, false);
    l_lane = __builtin_amdgcn_fdot2(a1, one2, l_lane, false);
    l_lane = __builtin_amdgcn_fdot2(b0, one2, l_lane, false);
    l_lane = __builtin_amdgcn_fdot2(b1, one2, l_lane, false);
    half4 pa = __builtin_shufflevector(a0, a1, 0, 1, 2, 3);
    half4 pb = __builtin_shufflevector(b0, b1, 0, 1, 2, 3);
    half8 pf = __builtin_shufflevector(pa, pb, 0, 4, 1, 5, 2, 6, 3, 7);

#pragma unroll
    for (int dt = 0; dt < 4; ++dt)
      o[dt] = __builtin_amdgcn_mfma_f32_16x16x32_f16(pf, vb[dt], o[dt], 0, 0, 0);
  };

  for (int t2 = 0; t2 < 18; ++t2) {
    // even tile (buf 0)
    body(bK0, bV0);
    __syncthreads();                 // kt=2*t2 <= 34 < 35 always
    if (t2 < 17) stage0();           // tile 2*t2+2 -> buf 0
    // odd tile (buf 1)
    body(bK1, bV1);
    if (t2 < 17) {
      __syncthreads();
      stage1();                      // tile 2*t2+3 -> buf 1
    }
  }

  __syncthreads();
  float* cO = (float*)smem;                   // [qgrp][dt][lane][4]
  float* cL = (float*)((char*)smem + 24576);  // [qgrp][lane]
  if (str == 1) {
    cL[qgrp * 64 + lane] = l_lane;
#pragma unroll
    for (int dt = 0; dt < 4; ++dt)
      *(floatx4*)&cO[((qgrp * 4 + dt) * 64 + lane) * 4] = o[dt];
  }
  __syncthreads();
  if (str == 0) {
    l_lane += cL[qgrp * 64 + lane];
#pragma unroll
    for (int dt = 0; dt < 4; ++dt)
      o[dt] += *(const floatx4*)&cO[((qgrp * 4 + dt) * 64 + lane) * 4];

    l_lane += __shfl_xor(l_lane, 16, 64);
    l_lane += __shfl_xor(l_lane, 32, 64);
    float inv[4];
#pragma unroll
    for (int r = 0; r < 4; ++r) {
      float lr = __shfl(l_lane, quad * 4 + r, 64);
      inv[r] = 1.f / lr;
    }
#pragma unroll
    for (int dt = 0; dt < 4; ++dt)
#pragma unroll
      for (int r = 0; r < 4; ++r) {
        int n_tok = m0 + qgrp * 16 + quad * 4 + r;
        int v = n_tok / 576, hw = n_tok % 576;
        int bb = g * 4 + v;
        int c = h * 64 + dt * 16 + l16;
        AOT[((size_t)bb * 576 + hw) * 512 + c] = (f16)(o[dt][r] * inv[r]);
      }
  }
}

// ---------------- proj GEMM: 32(o) x 96(t) tiles, dbuf — grid 768 = exactly 3/CU --
// R16: o-tile 64->32 => grid 16x48 = 768 blocks = 3/CU uniform (balance 75%->100%).
// 4 waves: (wo = wave&1) -> o-half 16; (wt = wave>>1) -> t-half 48 (3 frags).
__global__ __launch_bounds__(256) void k_proj_gemm(const f16* __restrict__ AOT,
                                                   const f16* __restrict__ WP,
                                                   const float* __restrict__ bias,
                                                   float* __restrict__ out) {
  const int o0 = blockIdx.x * 32, t0 = blockIdx.y * 96;
  __shared__ alignas(16) f16 smem[2 * 8192];  // 32 KB: [buf][A 2048 | B 6144]
  const int tid = threadIdx.x;
  const int wave = tid >> 6, lane = tid & 63, quad = lane >> 4, l16 = lane & 15;
  const int msub = (wave & 1) * 16, nsub = (wave >> 1) * 48;
  const floatx4 fzero = {0.f, 0.f, 0.f, 0.f};
  floatx4 acc[3];
  for (int j = 0; j < 3; ++j) acc[j] = fzero;

  auto stage = [&](int buf, int k0) {
    f16* dA = smem + buf * 8192;
    f16* dB = dA + 2048;
    {
      int e = tid;  // 256 units = 32 rows x 8 colb
      int row = e >> 3, colb = e & 7;
      async_cp16((const char*)WP + ((size_t)(o0 + row) * 512 + k0 + colb * 8) * 2,
                 (char*)dA + e * 16);
    }
#pragma unroll
    for (int p = 0; p < 3; ++p) {
      int e = p * 256 + tid;
      int row = e >> 3, colb = e & 7;
      async_cp16((const char*)AOT + ((size_t)(t0 + row) * 512 + k0 + colb * 8) * 2,
                 (char*)dB + e * 16);
    }
  };

  stage(0, 0);
  __syncthreads();
  for (int it = 0; it < 8; ++it) {
    int cur = it & 1;
    if (it < 7) stage(cur ^ 1, (it + 1) * 64);
    const f16* sA = smem + cur * 8192;
    const f16* sB = sA + 2048;
    for (int f = 0; f < 2; ++f) {
      half8 a, bfr[3];
      a = *(const half8*)&sA[(msub + l16) * 64 + f * 32 + quad * 8];
      for (int ns = 0; ns < 3; ++ns)
        bfr[ns] = *(const half8*)&sB[(nsub + ns * 16 + l16) * 64 + f * 32 + quad * 8];
      for (int ns = 0; ns < 3; ++ns)
        acc[ns] = __builtin_amdgcn_mfma_f32_16x16x32_f16(a, bfr[ns], acc[ns], 0, 0, 0);
    }
    __syncthreads();
  }
  {
    int o_row = o0 + msub + quad * 4;
    for (int ns = 0; ns < 3; ++ns) {
      int t = t0 + nsub + ns * 16 + l16;
      int b = t / 576, hw = t % 576;
      for (int r = 0; r < 4; ++r) {
        int orow = o_row + r;
        out[(size_t)b * 294912 + (size_t)orow * 576 + hw] = acc[ns][r] + bias[orow];
      }
    }
  }
}

extern "C" void kernel_launch(void* const* d_in, const int* in_sizes, int n_in,
                              void* d_out, int out_size, void* d_ws, size_t ws_size,
                              hipStream_t stream) {
  const float* x = (const float*)d_in[0];
  const float* wqkv = (const float*)d_in[1];
  const float* wproj = (const float*)d_in[2];
  const float* bias = (const float*)d_in[3];
  float* out = (float*)d_out;
  char* ws = (char*)d_ws;
  f16* XT = (f16*)(ws + 0);          // 4,718,592
  f16* WQ = (f16*)(ws + 4718592);    // 1,572,864
  f16* WP = (f16*)(ws + 6291456);    //   524,288
  f16* Qh = (f16*)(ws + 6815744);    // 4,718,592
  f16* Kh = (f16*)(ws + 11534336);   // 4,718,592
  f16* Vh = (f16*)(ws + 16252928);   // 4,718,592  ([gh][d][n'] key-interleaved)
  f16* AOT = (f16*)(ws + 20971520);  // 4,718,592

  k_prep<<<dim3(704), dim3(256), 0, stream>>>(x, XT, wqkv, wproj, WQ, WP);
  k_qkv_gemm<<<dim3(36, 12), dim3(256), 0, stream>>>(XT, WQ, Qh, Kh, Vh);
  k_attn<<<dim3(48, 16), dim3(384), 0, stream>>>(Qh, Kh, Vh, AOT);
  k_proj_gemm<<<dim3(16, 48), dim3(256), 0, stream>>>(AOT, WP, bias, out);
}